// Round 4
// baseline (7415.748 us; speedup 1.0000x reference)
//
#include <hip/hip_runtime.h>

#define NROWS 32768
#define DIM   512
#define NQ    8
#define NBINS 2048

// dist-GEMM tiling
#define BM 128
#define BN 128
#define BK 32
#define SRS (BM + 4)
#define SCS (BN + 4)
#define NTILES (NBINS / BN)     // 16 bin tiles

// ---------------------------------------------------------------------------
// numpy pairwise-sum combine: lanes 0..31 hold chain partials (g = lane>>3 block,
// j = lane&7 accumulator). xor-1,2,4 reproduce ((r0+r1)+(r2+r3))+((r4+r5)+(r6+r7));
// xor-8,16 reproduce (B0+B1)+(B2+B3). f32 add is commutative-exact, so shfl_xor
// pairing gives bit-identical results to numpy's written association.
__device__ inline float pw_combine(float s) {
#pragma unroll
    for (int m = 1; m <= 16; m <<= 1) {
        float o = __shfl_xor(s, m, 64);
        s = __fadd_rn(s, o);
    }
    return s;
}

// ---------------------------------------------------------------------------
// csq[q][b] = np.sum(c*c, -1) in exact numpy f32 pairwise semantics.
// One wave per codebook row, 32 active lanes (one per 16-term chain).
__global__ __launch_bounds__(256) void k_csq(const float* __restrict__ cb,
                                             float* __restrict__ csq32) {
    int row = blockIdx.x * 4 + (threadIdx.x >> 6);
    int lane = threadIdx.x & 63;
    const float* cp = cb + (size_t)row * DIM;
    float s = 0.0f;
    if (lane < 32) {
        int base = (lane >> 3) * 128 + (lane & 7);
        float e = cp[base];
        s = __fmul_rn(e, e);
#pragma unroll
        for (int m = 1; m < 16; ++m) {
            float e2 = cp[base + 8 * m];
            s = __fadd_rn(s, __fmul_rn(e2, e2));
        }
    }
    s = pw_combine(s);
    if (lane == 0) csq32[row] = s;
}

// ---------------------------------------------------------------------------
// residual update (init when cb==nullptr): rout = rin - cb[idx[row]] (f32, __fsub_rn)
// and r_sq = np.sum(r*r, -1) in exact numpy f32 pairwise semantics.
__global__ __launch_bounds__(128) void k_update(const float* __restrict__ rin,
                                                float* __restrict__ rout,
                                                const float* __restrict__ cb,
                                                const int* __restrict__ idx,
                                                float* __restrict__ rsq) {
    int row = blockIdx.x;
    int t = threadIdx.x;
    __shared__ float sq[DIM];
    const float* rp = rin + (size_t)row * DIM;
    float4 r = *(const float4*)(rp + t * 4);
    if (cb != nullptr) {
        const float* cp = cb + (size_t)idx[row] * DIM;
        float4 c = *(const float4*)(cp + t * 4);
        r.x = __fsub_rn(r.x, c.x);
        r.y = __fsub_rn(r.y, c.y);
        r.z = __fsub_rn(r.z, c.z);
        r.w = __fsub_rn(r.w, c.w);
    }
    *(float4*)(rout + (size_t)row * DIM + t * 4) = r;
    sq[t * 4 + 0] = __fmul_rn(r.x, r.x);
    sq[t * 4 + 1] = __fmul_rn(r.y, r.y);
    sq[t * 4 + 2] = __fmul_rn(r.z, r.z);
    sq[t * 4 + 3] = __fmul_rn(r.w, r.w);
    __syncthreads();
    if (t < 32) {
        int base = (t >> 3) * 128 + (t & 7);
        float s = sq[base];
#pragma unroll
        for (int m = 1; m < 16; ++m) s = __fadd_rn(s, sq[base + 8 * m]);
        s = pw_combine(s);
        if (t == 0) rsq[row] = s;
    }
}

// ---------------------------------------------------------------------------
// fused dist GEMM + per-row per-tile argmin.
// dot = single sequential f32 FMA chain over k ascending (== BLAS sgemm element).
// dist = (r_sq - 2*dot) + csq with explicit rounded ops (no contraction).
__global__ __launch_bounds__(256) void k_dist(const float* __restrict__ resid,
                                              const float* __restrict__ cb,
                                              const float* __restrict__ csq,
                                              const float* __restrict__ rsq,
                                              float* __restrict__ partD,   // [NROWS][NTILES]
                                              int* __restrict__ partI) {
    __shared__ __align__(16) float sR[BK * SRS];
    __shared__ __align__(16) float sC[BK * SCS];

    const int tid = threadIdx.x;
    const int binBase = blockIdx.x * BN;
    const int rowBase = blockIdx.y * BM;
    const int ty = tid >> 4;   // rows ty*8..+7
    const int tx = tid & 15;   // bins {tx*4..+3} u {64+tx*4..+3}

    const float* gR = resid + (size_t)rowBase * DIM;
    const float* gC = cb + (size_t)binBase * DIM;

    float acc[8][8];
#pragma unroll
    for (int i = 0; i < 8; ++i)
#pragma unroll
        for (int j = 0; j < 8; ++j) acc[i][j] = 0.0f;

    for (int k0 = 0; k0 < DIM; k0 += BK) {
        __syncthreads();
#pragma unroll
        for (int i = 0; i < 4; ++i) {
            int v = tid + i * 256;
            int row = v >> 3;
            int kk = (v & 7) << 2;
            float4 a = *(const float4*)(gR + (size_t)row * DIM + k0 + kk);
            sR[(kk + 0) * SRS + row] = a.x;
            sR[(kk + 1) * SRS + row] = a.y;
            sR[(kk + 2) * SRS + row] = a.z;
            sR[(kk + 3) * SRS + row] = a.w;
            float4 b = *(const float4*)(gC + (size_t)row * DIM + k0 + kk);
            sC[(kk + 0) * SCS + row] = b.x;
            sC[(kk + 1) * SCS + row] = b.y;
            sC[(kk + 2) * SCS + row] = b.z;
            sC[(kk + 3) * SCS + row] = b.w;
        }
        __syncthreads();
#pragma unroll 4
        for (int k = 0; k < BK; ++k) {
            float4 a0 = *(const float4*)&sR[k * SRS + ty * 8];
            float4 a1 = *(const float4*)&sR[k * SRS + ty * 8 + 4];
            float4 b0 = *(const float4*)&sC[k * SCS + tx * 4];
            float4 b1 = *(const float4*)&sC[k * SCS + 64 + tx * 4];
            float av[8] = {a0.x, a0.y, a0.z, a0.w, a1.x, a1.y, a1.z, a1.w};
            float bv[8] = {b0.x, b0.y, b0.z, b0.w, b1.x, b1.y, b1.z, b1.w};
#pragma unroll
            for (int i = 0; i < 8; ++i)
#pragma unroll
                for (int j = 0; j < 8; ++j)
                    acc[i][j] = fmaf(av[i], bv[j], acc[i][j]);
        }
    }

    // epilogue: exact-f32 dist, lex-min (first-index tie break == np.argmin)
    __syncthreads();
    float* bd = sR;                 // [BM][16]
    int* bi = (int*)sC;             // [BM][16]
#pragma unroll
    for (int i = 0; i < 8; ++i) {
        int row = ty * 8 + i;
        float rq = rsq[rowBase + row];
        float best = 3.4e38f;
        int bidx = 0x7fffffff;
#pragma unroll
        for (int j = 0; j < 8; ++j) {
            int bin = (j < 4) ? (tx * 4 + j) : (64 + tx * 4 + (j - 4));
            float d = __fadd_rn(__fsub_rn(rq, __fmul_rn(2.0f, acc[i][j])),
                                csq[binBase + bin]);
            if (d < best) { best = d; bidx = bin; }  // j ascending == bin ascending
        }
        bd[row * 16 + tx] = best;
        bi[row * 16 + tx] = binBase + bidx;
    }
    __syncthreads();
    if (tid < BM) {
        int row = tid;
        float best = bd[row * 16];
        int bidx = bi[row * 16];
        for (int t = 1; t < 16; ++t) {
            float d = bd[row * 16 + t];
            int i2 = bi[row * 16 + t];
            if (d < best || (d == best && i2 < bidx)) { best = d; bidx = i2; }
        }
        size_t g = (size_t)(rowBase + row);
        partD[g * NTILES + blockIdx.x] = best;
        partI[g * NTILES + blockIdx.x] = bidx;
    }
}

// ---------------------------------------------------------------------------
__global__ __launch_bounds__(256) void k_argmin(const float* __restrict__ partD,
                                                const int* __restrict__ partI,
                                                int* __restrict__ idxOut,
                                                float* __restrict__ codeOut) {
    int r = blockIdx.x * blockDim.x + threadIdx.x;
    if (r >= NROWS) return;
    size_t base = (size_t)r * NTILES;
    float best = partD[base];
    int bidx = partI[base];
    for (int t = 1; t < NTILES; ++t) {
        float d = partD[base + t];
        int i2 = partI[base + t];
        if (d < best || (d == best && i2 < bidx)) { best = d; bidx = i2; }
    }
    idxOut[r] = bidx;
    codeOut[r] = (float)bidx;
}

// ---------------------------------------------------------------------------
// quantized = hidden - residual_final (f32; within ~1e-5 of ref's sum-of-chosen)
__global__ __launch_bounds__(256) void k_quant(const float* __restrict__ h,
                                               const float* __restrict__ r,
                                               float* __restrict__ q) {
    size_t i = (size_t)blockIdx.x * blockDim.x + threadIdx.x;
    size_t base = i * 4;
    if (base >= (size_t)NROWS * DIM) return;
    float4 hv = *(const float4*)(h + base);
    float4 rv = *(const float4*)(r + base);
    float4 o;
    o.x = __fsub_rn(hv.x, rv.x);
    o.y = __fsub_rn(hv.y, rv.y);
    o.z = __fsub_rn(hv.z, rv.z);
    o.w = __fsub_rn(hv.w, rv.w);
    *(float4*)(q + base) = o;
}

// ---------------------------------------------------------------------------
extern "C" void kernel_launch(void* const* d_in, const int* in_sizes, int n_in,
                              void* d_out, int out_size, void* d_ws, size_t ws_size,
                              hipStream_t stream) {
    const float* hidden = (const float*)d_in[0];   // [NROWS][DIM]
    const float* cbs = (const float*)d_in[1];      // [NQ][NBINS][DIM]

    float* out_codes = (float*)d_out;                          // [NQ][NROWS] fp32
    float* out_quant = out_codes + (size_t)NQ * NROWS;         // [NROWS][DIM] fp32

    char* ws = (char*)d_ws;
    float* resid = (float*)ws;                                 // NROWS*DIM
    float* rsq = resid + (size_t)NROWS * DIM;                  // NROWS
    float* csq32 = rsq + NROWS;                                // NQ*NBINS
    int* idx = (int*)(csq32 + NQ * NBINS);                     // NROWS
    float* partD = (float*)(idx + NROWS);                      // NROWS*NTILES
    int* partI = (int*)(partD + (size_t)NROWS * NTILES);       // NROWS*NTILES

    k_csq<<<NQ * NBINS / 4, 256, 0, stream>>>(cbs, csq32);
    k_update<<<NROWS, 128, 0, stream>>>(hidden, resid, nullptr, nullptr, rsq);

    for (int s = 0; s < NQ; ++s) {
        const float* cbS = cbs + (size_t)s * NBINS * DIM;
        k_dist<<<dim3(NTILES, NROWS / BM), 256, 0, stream>>>(
            resid, cbS, csq32 + (size_t)s * NBINS, rsq, partD, partI);
        k_argmin<<<NROWS / 256, 256, 0, stream>>>(partD, partI, idx,
                                                  out_codes + (size_t)s * NROWS);
        k_update<<<NROWS, 128, 0, stream>>>(resid, resid, cbS, idx, rsq);
    }
    k_quant<<<(NROWS * DIM / 4) / 256, 256, 0, stream>>>(hidden, resid, out_quant);
}

// Round 5
// 1807.218 us; speedup vs baseline: 4.1034x; 4.1034x over previous
//
#include <hip/hip_runtime.h>
#include <hip/hip_bf16.h>

#define NROWS 32768
#define DIM   512
#define NQ    8
#define NBINS 2048

#define NTILES 16          // 2048 / 128 bins per tile
#define MARGIN 1.0f        // ~20 sigma of bf16 phase-1 noise

typedef __attribute__((ext_vector_type(8))) short short8v;
typedef __attribute__((ext_vector_type(4))) float f32x4;

__device__ inline unsigned short f2bf(float x) {
    __hip_bfloat16 h = __float2bfloat16(x);
    return *reinterpret_cast<unsigned short*>(&h);
}

typedef __attribute__((address_space(3))) void lds_t;
typedef __attribute__((address_space(1))) const void gbl_t;
__device__ inline void gload16(const void* g, void* l) {
    __builtin_amdgcn_global_load_lds((gbl_t*)g, (lds_t*)l, 16, 0, 0);
}

// ---------------------------------------------------------------------------
// numpy pairwise-sum combine (validated round 4)
__device__ inline float pw_combine(float s) {
#pragma unroll
    for (int m = 1; m <= 16; m <<= 1) {
        float o = __shfl_xor(s, m, 64);
        s = __fadd_rn(s, o);
    }
    return s;
}

// csq = np.sum(c*c,-1) exact numpy f32 pairwise semantics (validated round 4)
__global__ __launch_bounds__(256) void k_csq(const float* __restrict__ cb,
                                             float* __restrict__ csq32) {
    int row = blockIdx.x * 4 + (threadIdx.x >> 6);
    int lane = threadIdx.x & 63;
    const float* cp = cb + (size_t)row * DIM;
    float s = 0.0f;
    if (lane < 32) {
        int base = (lane >> 3) * 128 + (lane & 7);
        float e = cp[base];
        s = __fmul_rn(e, e);
#pragma unroll
        for (int m = 1; m < 16; ++m) {
            float e2 = cp[base + 8 * m];
            s = __fadd_rn(s, __fmul_rn(e2, e2));
        }
    }
    s = pw_combine(s);
    if (lane == 0) csq32[row] = s;
}

// ---------------------------------------------------------------------------
// codebooks fp32 -> bf16 (one shot, all stages)
__global__ __launch_bounds__(256) void k_cbf(const float* __restrict__ cb,
                                             unsigned short* __restrict__ o) {
    size_t base = ((size_t)blockIdx.x * 256 + threadIdx.x) * 8;
    float4 a = *(const float4*)(cb + base);
    float4 b = *(const float4*)(cb + base + 4);
    short8v v;
    v[0] = f2bf(a.x); v[1] = f2bf(a.y); v[2] = f2bf(a.z); v[3] = f2bf(a.w);
    v[4] = f2bf(b.x); v[5] = f2bf(b.y); v[6] = f2bf(b.z); v[7] = f2bf(b.w);
    *(short8v*)(o + base) = v;
}

// ---------------------------------------------------------------------------
// exact fp32 residual update (init when cb==nullptr) + np-exact rsq
// + bf16 copy of the residual for the MFMA phase-1 of the next stage.
__global__ __launch_bounds__(128) void k_update(const float* __restrict__ rin,
                                                float* __restrict__ rout,
                                                const float* __restrict__ cb,
                                                const int* __restrict__ idx,
                                                float* __restrict__ rsq,
                                                unsigned short* __restrict__ ahi) {
    int row = blockIdx.x;
    int t = threadIdx.x;
    __shared__ float sq[DIM];
    const float* rp = rin + (size_t)row * DIM;
    float4 r = *(const float4*)(rp + t * 4);
    if (cb != nullptr) {
        const float* cp = cb + (size_t)idx[row] * DIM;
        float4 c = *(const float4*)(cp + t * 4);
        r.x = __fsub_rn(r.x, c.x);
        r.y = __fsub_rn(r.y, c.y);
        r.z = __fsub_rn(r.z, c.z);
        r.w = __fsub_rn(r.w, c.w);
    }
    *(float4*)(rout + (size_t)row * DIM + t * 4) = r;
    ushort4 hv;
    hv.x = f2bf(r.x); hv.y = f2bf(r.y); hv.z = f2bf(r.z); hv.w = f2bf(r.w);
    *(ushort4*)(ahi + (size_t)row * DIM + t * 4) = hv;

    sq[t * 4 + 0] = __fmul_rn(r.x, r.x);
    sq[t * 4 + 1] = __fmul_rn(r.y, r.y);
    sq[t * 4 + 2] = __fmul_rn(r.z, r.z);
    sq[t * 4 + 3] = __fmul_rn(r.w, r.w);
    __syncthreads();
    if (t < 32) {
        int base = (t >> 3) * 128 + (t & 7);
        float s = sq[base];
#pragma unroll
        for (int m = 1; m < 16; ++m) s = __fadd_rn(s, sq[base + 8 * m]);
        s = pw_combine(s);
        if (t == 0) rsq[row] = s;
    }
}

// ---------------------------------------------------------------------------
// phase-1: bf16 MFMA GEMM (128x128 tile, BK=32, m97 structure) computing
// dist' = csq - 2*dot~ and per-row TOP-4 per 128-bin tile.
__global__ __launch_bounds__(256) void k_gemm(const unsigned short* __restrict__ Ahi,
                                              const unsigned short* __restrict__ Bcb,
                                              const float* __restrict__ csq,
                                              float* __restrict__ partD,   // [NROWS][16][4]
                                              int* __restrict__ partI) {
    __shared__ __align__(16) char ldsraw[33280];   // union: stage(16KB) | dist 128x65 f32
    __shared__ float csqS[128];

    const int tid = threadIdx.x;
    const int lane = tid & 63;
    const int w = tid >> 6;
    const int wr = w >> 1;      // wave row block (0..1)
    const int wc = w & 1;       // wave col block (0..1)
    const int binBase = blockIdx.x * 128;
    const int rowBase = blockIdx.y * 128;

    if (tid < 128) csqS[tid] = csq[binBase + tid];

    const char* Abase = (const char*)(Ahi + (size_t)rowBase * DIM);
    const char* Bbase = (const char*)(Bcb + (size_t)binBase * DIM);

    f32x4 acc[4][4];
#pragma unroll
    for (int m = 0; m < 4; ++m)
#pragma unroll
        for (int n = 0; n < 4; ++n) acc[m][n] = (f32x4){0.f, 0.f, 0.f, 0.f};

    const int o0 = tid * 16;          // LDS byte offset, issue 0 (rows 0..63)
    const int o1 = o0 + 4096;         // issue 1 (rows 64..127)
    const int kb16 = (lane >> 4) * 16;                    // k-slice byte offset
    const int ra = (wr * 64 + (lane & 15)) * 64 + kb16;   // A frag base byte
    const int rb = (wc * 64 + (lane & 15)) * 64 + kb16;   // B frag base byte

    for (int ks = 0; ks < DIM / 32; ++ks) {
        const int k0b = ks * 64;      // K-step byte offset within a row
        __syncthreads();
        // stage A tile [128][32] bf16 (8KB) and B tile (8KB), LDS-linear
        gload16(Abase + (size_t)(o0 >> 6) * (DIM * 2) + k0b + (o0 & 63), ldsraw + o0);
        gload16(Abase + (size_t)(o1 >> 6) * (DIM * 2) + k0b + (o1 & 63), ldsraw + o1);
        gload16(Bbase + (size_t)(o0 >> 6) * (DIM * 2) + k0b + (o0 & 63), ldsraw + 8192 + o0);
        gload16(Bbase + (size_t)(o1 >> 6) * (DIM * 2) + k0b + (o1 & 63), ldsraw + 8192 + o1);
        __syncthreads();

        short8v aF[4], bF[4];
#pragma unroll
        for (int m = 0; m < 4; ++m)
            aF[m] = *(const short8v*)(ldsraw + ra + m * 1024);
#pragma unroll
        for (int n = 0; n < 4; ++n)
            bF[n] = *(const short8v*)(ldsraw + 8192 + rb + n * 1024);
#pragma unroll
        for (int m = 0; m < 4; ++m)
#pragma unroll
            for (int n = 0; n < 4; ++n)
                acc[m][n] = __builtin_amdgcn_mfma_f32_16x16x32_bf16(
                    aF[m], bF[n], acc[m][n], 0, 0, 0);
    }

    // epilogue: 2 phases (bins 0-63 then 64-127) through a [128][65] LDS tile
    float* distf = (float*)ldsraw;
    float td0 = 3.4e38f, td1 = 3.4e38f, td2 = 3.4e38f, td3 = 3.4e38f;
    int ti0 = 0x7fffffff, ti1 = 0x7fffffff, ti2 = 0x7fffffff, ti3 = 0x7fffffff;

#pragma unroll
    for (int phase = 0; phase < 2; ++phase) {
        __syncthreads();
        if (wc == phase) {
#pragma unroll
            for (int m = 0; m < 4; ++m)
#pragma unroll
                for (int n = 0; n < 4; ++n)
#pragma unroll
                    for (int r = 0; r < 4; ++r) {
                        int row = wr * 64 + m * 16 + (lane >> 4) * 4 + r;
                        int col = n * 16 + (lane & 15);
                        distf[row * 65 + col] = csqS[phase * 64 + col] - 2.0f * acc[m][n][r];
                    }
        }
        __syncthreads();
        if (tid < 128) {
            for (int c = 0; c < 64; ++c) {
                float d = distf[tid * 65 + c];
                int bin = binBase + phase * 64 + c;
                if (d < td3) {
                    if (d < td2) {
                        td3 = td2; ti3 = ti2;
                        if (d < td1) {
                            td2 = td1; ti2 = ti1;
                            if (d < td0) { td1 = td0; ti1 = ti0; td0 = d; ti0 = bin; }
                            else { td1 = d; ti1 = bin; }
                        } else { td2 = d; ti2 = bin; }
                    } else { td3 = d; ti3 = bin; }
                }
            }
        }
    }
    if (tid < 128) {
        size_t g = (size_t)(rowBase + tid) * 64 + blockIdx.x * 4;
        partD[g + 0] = td0; partI[g + 0] = ti0;
        partD[g + 1] = td1; partI[g + 1] = ti1;
        partD[g + 2] = td2; partI[g + 2] = ti2;
        partD[g + 3] = td3; partI[g + 3] = ti3;
    }
}

// ---------------------------------------------------------------------------
// phase-2: candidate resolve. One wave per row. If a single entry is within
// MARGIN of the min, it is the argmin; else rescore candidates with the
// bit-exact numpy fp32 pipeline (validated round 4).
__global__ __launch_bounds__(256) void k_refine(const float* __restrict__ partD,
                                                const int* __restrict__ partI,
                                                const float* __restrict__ resid,
                                                const float* __restrict__ rsq,
                                                const float* __restrict__ csq,   // stage [NBINS]
                                                const float* __restrict__ cb,    // stage fp32
                                                int* __restrict__ idxOut,
                                                float* __restrict__ codeOut) {
    int row = blockIdx.x * 4 + (threadIdx.x >> 6);
    int lane = threadIdx.x & 63;

    float d = partD[(size_t)row * 64 + lane];
    int bi0 = partI[(size_t)row * 64 + lane];

    float bd = d; int bix = bi0;
#pragma unroll
    for (int o = 32; o > 0; o >>= 1) {
        float od = __shfl_xor(bd, o);
        int oi = __shfl_xor(bix, o);
        if (od < bd || (od == bd && oi < bix)) { bd = od; bix = oi; }
    }
    bool cand = (d <= bd + MARGIN);
    unsigned long long mask = __ballot(cand);
    int winI;
    if (__popcll(mask) == 1) {
        winI = bix;
    } else {
        float myD = 3.4e38f; int myI = 0x7fffffff;
        if (cand) {
            const float* rp = resid + (size_t)row * DIM;
            const float* cp = cb + (size_t)bi0 * DIM;
            float acc = 0.0f;
            for (int k = 0; k < DIM; k += 4) {
                float4 rv = *(const float4*)(rp + k);
                float4 cv = *(const float4*)(cp + k);
                acc = fmaf(rv.x, cv.x, acc);
                acc = fmaf(rv.y, cv.y, acc);
                acc = fmaf(rv.z, cv.z, acc);
                acc = fmaf(rv.w, cv.w, acc);
            }
            myD = __fadd_rn(__fsub_rn(rsq[row], __fmul_rn(2.0f, acc)), csq[bi0]);
            myI = bi0;
        }
#pragma unroll
        for (int o = 32; o > 0; o >>= 1) {
            float od = __shfl_xor(myD, o);
            int oi = __shfl_xor(myI, o);
            if (od < myD || (od == myD && oi < myI)) { myD = od; myI = oi; }
        }
        winI = myI;
    }
    if (lane == 0) {
        idxOut[row] = winI;
        codeOut[row] = (float)winI;
    }
}

// ---------------------------------------------------------------------------
// quantized = hidden - residual, IN PLACE (residual lives in the quant region)
__global__ __launch_bounds__(256) void k_quant(const float* __restrict__ h,
                                               float* __restrict__ q) {
    size_t base = ((size_t)blockIdx.x * 256 + threadIdx.x) * 4;
    float4 rv = *(const float4*)(q + base);
    float4 hv = *(const float4*)(h + base);
    float4 o;
    o.x = __fsub_rn(hv.x, rv.x);
    o.y = __fsub_rn(hv.y, rv.y);
    o.z = __fsub_rn(hv.z, rv.z);
    o.w = __fsub_rn(hv.w, rv.w);
    *(float4*)(q + base) = o;
}

// ---------------------------------------------------------------------------
extern "C" void kernel_launch(void* const* d_in, const int* in_sizes, int n_in,
                              void* d_out, int out_size, void* d_ws, size_t ws_size,
                              hipStream_t stream) {
    const float* hidden = (const float*)d_in[0];   // [NROWS][DIM]
    const float* cbs = (const float*)d_in[1];      // [NQ][NBINS][DIM]

    float* out_codes = (float*)d_out;                          // [NQ][NROWS]
    float* resid = out_codes + (size_t)NQ * NROWS;             // quant region doubles as residual

    // workspace (~67 MB)
    unsigned short* Ahi = (unsigned short*)d_ws;               // NROWS*DIM bf16
    unsigned short* Cbf = Ahi + (size_t)NROWS * DIM;           // NQ*NBINS*DIM bf16
    float* csq32 = (float*)(Cbf + (size_t)NQ * NBINS * DIM);   // NQ*NBINS
    float* rsq = csq32 + (size_t)NQ * NBINS;                   // NROWS
    int* idx = (int*)(rsq + NROWS);                            // NROWS
    float* partD = (float*)(idx + NROWS);                      // NROWS*64
    int* partI = (int*)(partD + (size_t)NROWS * 64);           // NROWS*64

    k_csq<<<NQ * NBINS / 4, 256, 0, stream>>>(cbs, csq32);
    k_cbf<<<(int)((size_t)NQ * NBINS * DIM / 8 / 256), 256, 0, stream>>>(cbs, Cbf);
    k_update<<<NROWS, 128, 0, stream>>>(hidden, resid, nullptr, nullptr, rsq, Ahi);

    for (int s = 0; s < NQ; ++s) {
        const float* cbS = cbs + (size_t)s * NBINS * DIM;
        k_gemm<<<dim3(NTILES, NROWS / 128), 256, 0, stream>>>(
            Ahi, Cbf + (size_t)s * NBINS * DIM, csq32 + (size_t)s * NBINS,
            partD, partI);
        k_refine<<<NROWS / 4, 256, 0, stream>>>(partD, partI, resid, rsq,
                                                csq32 + (size_t)s * NBINS, cbS,
                                                idx, out_codes + (size_t)s * NROWS);
        k_update<<<NROWS, 128, 0, stream>>>(resid, resid, cbS, idx, rsq, Ahi);
    }
    k_quant<<<NROWS * DIM / 4 / 256, 256, 0, stream>>>(hidden, resid);
}

// Round 7
// 1564.873 us; speedup vs baseline: 4.7389x; 1.1549x over previous
//
#include <hip/hip_runtime.h>
#include <hip/hip_bf16.h>

#define NROWS 32768
#define DIM   512
#define NQ    8
#define NBINS 2048

#define NTILE2 8           // 2048 / 256 bins per block
#define MARGIN 1.0f        // ~20 sigma of bf16 phase-1 noise (validated round 5)

typedef __attribute__((ext_vector_type(8))) short short8v;
typedef __attribute__((ext_vector_type(4))) float f32x4;

__device__ inline unsigned short f2bf(float x) {
    __hip_bfloat16 h = __float2bfloat16(x);
    return *reinterpret_cast<unsigned short*>(&h);
}

typedef __attribute__((address_space(3))) void lds_t;
typedef __attribute__((address_space(1))) const void gbl_t;
__device__ inline void gload16(const void* g, void* l) {
    __builtin_amdgcn_global_load_lds((gbl_t*)g, (lds_t*)l, 16, 0, 0);
}

// ---------------------------------------------------------------------------
// numpy pairwise-sum combine (validated round 4)
__device__ inline float pw_combine(float s) {
#pragma unroll
    for (int m = 1; m <= 16; m <<= 1) {
        float o = __shfl_xor(s, m, 64);
        s = __fadd_rn(s, o);
    }
    return s;
}

// csq = np.sum(c*c,-1) exact numpy f32 pairwise semantics (validated round 4)
__global__ __launch_bounds__(256) void k_csq(const float* __restrict__ cb,
                                             float* __restrict__ csq32) {
    int row = blockIdx.x * 4 + (threadIdx.x >> 6);
    int lane = threadIdx.x & 63;
    const float* cp = cb + (size_t)row * DIM;
    float s = 0.0f;
    if (lane < 32) {
        int base = (lane >> 3) * 128 + (lane & 7);
        float e = cp[base];
        s = __fmul_rn(e, e);
#pragma unroll
        for (int m = 1; m < 16; ++m) {
            float e2 = cp[base + 8 * m];
            s = __fadd_rn(s, __fmul_rn(e2, e2));
        }
    }
    s = pw_combine(s);
    if (lane == 0) csq32[row] = s;
}

// ---------------------------------------------------------------------------
// codebooks fp32 -> bf16 (one shot, all stages)
__global__ __launch_bounds__(256) void k_cbf(const float* __restrict__ cb,
                                             unsigned short* __restrict__ o) {
    size_t base = ((size_t)blockIdx.x * 256 + threadIdx.x) * 8;
    float4 a = *(const float4*)(cb + base);
    float4 b = *(const float4*)(cb + base + 4);
    short8v v;
    v[0] = f2bf(a.x); v[1] = f2bf(a.y); v[2] = f2bf(a.z); v[3] = f2bf(a.w);
    v[4] = f2bf(b.x); v[5] = f2bf(b.y); v[6] = f2bf(b.z); v[7] = f2bf(b.w);
    *(short8v*)(o + base) = v;
}

// ---------------------------------------------------------------------------
// exact fp32 residual update (init when cb==nullptr) + np-exact rsq
// + bf16 copy of the residual for the MFMA phase-1 of the next stage.
__global__ __launch_bounds__(128) void k_update(const float* __restrict__ rin,
                                                float* __restrict__ rout,
                                                const float* __restrict__ cb,
                                                const int* __restrict__ idx,
                                                float* __restrict__ rsq,
                                                unsigned short* __restrict__ ahi) {
    int row = blockIdx.x;
    int t = threadIdx.x;
    __shared__ float sq[DIM];
    const float* rp = rin + (size_t)row * DIM;
    float4 r = *(const float4*)(rp + t * 4);
    if (cb != nullptr) {
        const float* cp = cb + (size_t)idx[row] * DIM;
        float4 c = *(const float4*)(cp + t * 4);
        r.x = __fsub_rn(r.x, c.x);
        r.y = __fsub_rn(r.y, c.y);
        r.z = __fsub_rn(r.z, c.z);
        r.w = __fsub_rn(r.w, c.w);
    }
    *(float4*)(rout + (size_t)row * DIM + t * 4) = r;
    ushort4 hv;
    hv.x = f2bf(r.x); hv.y = f2bf(r.y); hv.z = f2bf(r.z); hv.w = f2bf(r.w);
    *(ushort4*)(ahi + (size_t)row * DIM + t * 4) = hv;

    sq[t * 4 + 0] = __fmul_rn(r.x, r.x);
    sq[t * 4 + 1] = __fmul_rn(r.y, r.y);
    sq[t * 4 + 2] = __fmul_rn(r.z, r.z);
    sq[t * 4 + 3] = __fmul_rn(r.w, r.w);
    __syncthreads();
    if (t < 32) {
        int base = (t >> 3) * 128 + (t & 7);
        float s = sq[base];
#pragma unroll
        for (int m = 1; m < 16; ++m) s = __fadd_rn(s, sq[base + 8 * m]);
        s = pw_combine(s);
        if (t == 0) rsq[row] = s;
    }
}

// ---------------------------------------------------------------------------
// staging: A tile [256][64]bf16 (32KB) + B tile [256][64]bf16 (32KB).
// 2048 16B-chunks per matrix = 4 iterations x 512 threads.  (Round-6 bug:
// i<2 staged only half the tile.)  LDS dest is LINEAR; the chunk swizzle
// (c ^ (row&7)) is applied to the GLOBAL source (both-sides rule).
__device__ inline void stage_tile(const char* Abase, const char* Bbase,
                                  char* buf, int tid, int k0b) {
#pragma unroll
    for (int i = 0; i < 4; ++i) {
        int L = i * 512 + tid;
        int row = L >> 3, cc = L & 7;
        int sw = ((cc ^ (row & 7)) << 4);
        gload16(Abase + (size_t)row * (DIM * 2) + k0b + sw, buf + L * 16);
        gload16(Bbase + (size_t)row * (DIM * 2) + k0b + sw, buf + 32768 + L * 16);
    }
}

// ---------------------------------------------------------------------------
// phase-1: bf16 MFMA GEMM, 256x256 tile, BK=64, 8 waves, double-buffered LDS
// with issue-early/drain-late prefetch (T3-minimum). Computes
// dist' = csq - 2*dot~ and per-row running top-4 per col-half (8 cand/tile).
__global__ __launch_bounds__(512) void k_gemm(const unsigned short* __restrict__ Ahi,
                                              const unsigned short* __restrict__ Bcb,
                                              const float* __restrict__ csq,
                                              float* __restrict__ partD,   // [NROWS][64]
                                              int* __restrict__ partI) {
    __shared__ __align__(16) char lds[131072];   // 2 buffers x (A 32KB | B 32KB)
    __shared__ float csqS[256];

    const int tid = threadIdx.x;
    const int lane = tid & 63;
    const int w = tid >> 6;
    const int wr = w >> 2;      // 0..1 : 128-row half
    const int wc = w & 3;       // 0..3 : 64-col group

    // XCD-aware decode: presumed XCD = wg&7 owns 16 contiguous row panels
    // (A set = 4MB = one L2) and sweeps the 8 bin tiles sequentially.
    const int wg = blockIdx.x;
    const int panel = (wg & 7) * 16 + ((wg >> 3) & 15);   // 0..127
    const int T = wg >> 7;                                 // 0..7

    if (tid < 256) csqS[tid] = csq[T * 256 + tid];

    const char* Abase = (const char*)(Ahi + (size_t)panel * 256 * DIM);
    const char* Bbase = (const char*)(Bcb + (size_t)T * 256 * DIM);

    f32x4 acc[8][4];
#pragma unroll
    for (int m = 0; m < 8; ++m)
#pragma unroll
        for (int n = 0; n < 4; ++n) acc[m][n] = (f32x4){0.f, 0.f, 0.f, 0.f};

    int cur = 0;
    stage_tile(Abase, Bbase, lds, tid, 0);
    __syncthreads();

    for (int ks = 0; ks < 8; ++ks) {
        if (ks < 7)
            stage_tile(Abase, Bbase, lds + (cur ^ 1) * 65536, tid, (ks + 1) * 128);
        const char* Ab = lds + cur * 65536;
        const char* Bb = Ab + 32768;
#pragma unroll
        for (int kk = 0; kk < 2; ++kk) {
            const int sw = (((kk * 4 + (lane >> 4)) ^ (lane & 7)) << 4);
            short8v bF[4];
#pragma unroll
            for (int n = 0; n < 4; ++n) {
                int rowB = wc * 64 + n * 16 + (lane & 15);
                bF[n] = *(const short8v*)(Bb + rowB * 128 + sw);
            }
#pragma unroll
            for (int m = 0; m < 8; ++m) {
                int rowA = wr * 128 + m * 16 + (lane & 15);
                short8v aF = *(const short8v*)(Ab + rowA * 128 + sw);
#pragma unroll
                for (int n = 0; n < 4; ++n)
                    acc[m][n] = __builtin_amdgcn_mfma_f32_16x16x32_bf16(
                        aF, bF[n], acc[m][n], 0, 0, 0);
            }
        }
        __syncthreads();
        cur ^= 1;
    }

    // epilogue: 4 phases through a [256][66] f32 LDS tile (reuses staging LDS).
    // Thread (row2,h) keeps a running top-4 over its 128 scanned cols;
    // two top-4s per row per tile stored (8 candidates/tile).
    float td0 = 3.4e38f, td1 = 3.4e38f, td2 = 3.4e38f, td3 = 3.4e38f;
    int ti0 = 0, ti1 = 0, ti2 = 0, ti3 = 0;
    float* distf = (float*)lds;
    const int row2 = tid >> 1, h = tid & 1;

#pragma unroll
    for (int p = 0; p < 4; ++p) {
        __syncthreads();
        if (wc == p) {
#pragma unroll
            for (int m = 0; m < 8; ++m)
#pragma unroll
                for (int n = 0; n < 4; ++n)
#pragma unroll
                    for (int r = 0; r < 4; ++r) {
                        int row = wr * 128 + m * 16 + (lane >> 4) * 4 + r;
                        int cl = n * 16 + (lane & 15);
                        distf[row * 66 + cl] = csqS[p * 64 + cl] - 2.0f * acc[m][n][r];
                    }
        }
        __syncthreads();
        int binb = T * 256 + p * 64 + h * 32;
        for (int c = 0; c < 32; ++c) {
            float d = distf[row2 * 66 + h * 32 + c];
            int bin = binb + c;
            if (d < td3) {
                if (d < td2) {
                    td3 = td2; ti3 = ti2;
                    if (d < td1) {
                        td2 = td1; ti2 = ti1;
                        if (d < td0) { td1 = td0; ti1 = ti0; td0 = d; ti0 = bin; }
                        else { td1 = d; ti1 = bin; }
                    } else { td2 = d; ti2 = bin; }
                } else { td3 = d; ti3 = bin; }
            }
        }
    }
    size_t g = ((size_t)panel * 256 + row2) * 64 + T * 8 + h * 4;
    partD[g + 0] = td0; partI[g + 0] = ti0;
    partD[g + 1] = td1; partI[g + 1] = ti1;
    partD[g + 2] = td2; partI[g + 2] = ti2;
    partD[g + 3] = td3; partI[g + 3] = ti3;
}

// ---------------------------------------------------------------------------
// phase-2: candidate resolve. One wave per row. If a single entry is within
// MARGIN of the min, it is the argmin; else rescore candidates with the
// bit-exact numpy fp32 pipeline (validated round 4).
__global__ __launch_bounds__(256) void k_refine(const float* __restrict__ partD,
                                                const int* __restrict__ partI,
                                                const float* __restrict__ resid,
                                                const float* __restrict__ rsq,
                                                const float* __restrict__ csq,   // stage [NBINS]
                                                const float* __restrict__ cb,    // stage fp32
                                                int* __restrict__ idxOut,
                                                float* __restrict__ codeOut) {
    int row = blockIdx.x * 4 + (threadIdx.x >> 6);
    int lane = threadIdx.x & 63;

    float d = partD[(size_t)row * 64 + lane];
    int bi0 = partI[(size_t)row * 64 + lane];

    float bd = d; int bix = bi0;
#pragma unroll
    for (int o = 32; o > 0; o >>= 1) {
        float od = __shfl_xor(bd, o);
        int oi = __shfl_xor(bix, o);
        if (od < bd || (od == bd && oi < bix)) { bd = od; bix = oi; }
    }
    bool cand = (d <= bd + MARGIN);
    unsigned long long mask = __ballot(cand);
    int winI;
    if (__popcll(mask) == 1) {
        winI = bix;
    } else {
        float myD = 3.4e38f; int myI = 0x7fffffff;
        if (cand) {
            const float* rp = resid + (size_t)row * DIM;
            const float* cp = cb + (size_t)bi0 * DIM;
            float acc = 0.0f;
            for (int k = 0; k < DIM; k += 4) {
                float4 rv = *(const float4*)(rp + k);
                float4 cv = *(const float4*)(cp + k);
                acc = fmaf(rv.x, cv.x, acc);
                acc = fmaf(rv.y, cv.y, acc);
                acc = fmaf(rv.z, cv.z, acc);
                acc = fmaf(rv.w, cv.w, acc);
            }
            myD = __fadd_rn(__fsub_rn(rsq[row], __fmul_rn(2.0f, acc)), csq[bi0]);
            myI = bi0;
        }
#pragma unroll
        for (int o = 32; o > 0; o >>= 1) {
            float od = __shfl_xor(myD, o);
            int oi = __shfl_xor(myI, o);
            if (od < myD || (od == myD && oi < myI)) { myD = od; myI = oi; }
        }
        winI = myI;
    }
    if (lane == 0) {
        idxOut[row] = winI;
        codeOut[row] = (float)winI;
    }
}

// ---------------------------------------------------------------------------
// quantized = hidden - residual, IN PLACE (residual lives in the quant region)
__global__ __launch_bounds__(256) void k_quant(const float* __restrict__ h,
                                               float* __restrict__ q) {
    size_t base = ((size_t)blockIdx.x * 256 + threadIdx.x) * 4;
    float4 rv = *(const float4*)(q + base);
    float4 hv = *(const float4*)(h + base);
    float4 o;
    o.x = __fsub_rn(hv.x, rv.x);
    o.y = __fsub_rn(hv.y, rv.y);
    o.z = __fsub_rn(hv.z, rv.z);
    o.w = __fsub_rn(hv.w, rv.w);
    *(float4*)(q + base) = o;
}

// ---------------------------------------------------------------------------
extern "C" void kernel_launch(void* const* d_in, const int* in_sizes, int n_in,
                              void* d_out, int out_size, void* d_ws, size_t ws_size,
                              hipStream_t stream) {
    const float* hidden = (const float*)d_in[0];   // [NROWS][DIM]
    const float* cbs = (const float*)d_in[1];      // [NQ][NBINS][DIM]

    float* out_codes = (float*)d_out;                          // [NQ][NROWS]
    float* resid = out_codes + (size_t)NQ * NROWS;             // quant region doubles as residual

    // workspace (~67 MB)
    unsigned short* Ahi = (unsigned short*)d_ws;               // NROWS*DIM bf16
    unsigned short* Cbf = Ahi + (size_t)NROWS * DIM;           // NQ*NBINS*DIM bf16
    float* csq32 = (float*)(Cbf + (size_t)NQ * NBINS * DIM);   // NQ*NBINS
    float* rsq = csq32 + (size_t)NQ * NBINS;                   // NROWS
    int* idx = (int*)(rsq + NROWS);                            // NROWS
    float* partD = (float*)(idx + NROWS);                      // NROWS*64
    int* partI = (int*)(partD + (size_t)NROWS * 64);           // NROWS*64

    k_csq<<<NQ * NBINS / 4, 256, 0, stream>>>(cbs, csq32);
    k_cbf<<<(int)((size_t)NQ * NBINS * DIM / 8 / 256), 256, 0, stream>>>(cbs, Cbf);
    k_update<<<NROWS, 128, 0, stream>>>(hidden, resid, nullptr, nullptr, rsq, Ahi);

    for (int s = 0; s < NQ; ++s) {
        const float* cbS = cbs + (size_t)s * NBINS * DIM;
        k_gemm<<<(NROWS / 256) * NTILE2, 512, 0, stream>>>(
            Ahi, Cbf + (size_t)s * NBINS * DIM, csq32 + (size_t)s * NBINS,
            partD, partI);
        k_refine<<<NROWS / 4, 256, 0, stream>>>(partD, partI, resid, rsq,
                                                csq32 + (size_t)s * NBINS, cbS,
                                                idx, out_codes + (size_t)s * NROWS);
        k_update<<<NROWS, 128, 0, stream>>>(resid, resid, cbS, idx, rsq, Ahi);
    }
    k_quant<<<NROWS * DIM / 4 / 256, 256, 0, stream>>>(hidden, resid);
}

// Round 8
// 1537.374 us; speedup vs baseline: 4.8236x; 1.0179x over previous
//
#include <hip/hip_runtime.h>
#include <hip/hip_bf16.h>

#define NROWS 32768
#define DIM   512
#define NQ    8
#define NBINS 2048

#define NTILE2 8           // 2048 / 256 bins per block
#define MARGIN 1.0f        // ~20 sigma of bf16 phase-1 noise (validated rounds 5/7)

typedef __attribute__((ext_vector_type(8))) short short8v;
typedef __attribute__((ext_vector_type(4))) float f32x4;

__device__ inline unsigned short f2bf(float x) {
    __hip_bfloat16 h = __float2bfloat16(x);
    return *reinterpret_cast<unsigned short*>(&h);
}

typedef __attribute__((address_space(3))) void lds_t;
typedef __attribute__((address_space(1))) const void gbl_t;
__device__ inline void gload16(const void* g, void* l) {
    __builtin_amdgcn_global_load_lds((gbl_t*)g, (lds_t*)l, 16, 0, 0);
}

// ---------------------------------------------------------------------------
// numpy pairwise-sum combine (validated round 4)
__device__ inline float pw_combine(float s) {
#pragma unroll
    for (int m = 1; m <= 16; m <<= 1) {
        float o = __shfl_xor(s, m, 64);
        s = __fadd_rn(s, o);
    }
    return s;
}

// csq = np.sum(c*c,-1) exact numpy f32 pairwise semantics (validated round 4)
__global__ __launch_bounds__(256) void k_csq(const float* __restrict__ cb,
                                             float* __restrict__ csq32) {
    int row = blockIdx.x * 4 + (threadIdx.x >> 6);
    int lane = threadIdx.x & 63;
    const float* cp = cb + (size_t)row * DIM;
    float s = 0.0f;
    if (lane < 32) {
        int base = (lane >> 3) * 128 + (lane & 7);
        float e = cp[base];
        s = __fmul_rn(e, e);
#pragma unroll
        for (int m = 1; m < 16; ++m) {
            float e2 = cp[base + 8 * m];
            s = __fadd_rn(s, __fmul_rn(e2, e2));
        }
    }
    s = pw_combine(s);
    if (lane == 0) csq32[row] = s;
}

// ---------------------------------------------------------------------------
// codebooks fp32 -> bf16 (one shot, all stages)
__global__ __launch_bounds__(256) void k_cbf(const float* __restrict__ cb,
                                             unsigned short* __restrict__ o) {
    size_t base = ((size_t)blockIdx.x * 256 + threadIdx.x) * 8;
    float4 a = *(const float4*)(cb + base);
    float4 b = *(const float4*)(cb + base + 4);
    short8v v;
    v[0] = f2bf(a.x); v[1] = f2bf(a.y); v[2] = f2bf(a.z); v[3] = f2bf(a.w);
    v[4] = f2bf(b.x); v[5] = f2bf(b.y); v[6] = f2bf(b.z); v[7] = f2bf(b.w);
    *(short8v*)(o + base) = v;
}

// ---------------------------------------------------------------------------
// initial residual (= hidden) + np-exact rsq + bf16 copy for the MFMA phase.
__global__ __launch_bounds__(128) void k_init(const float* __restrict__ h,
                                              float* __restrict__ rout,
                                              float* __restrict__ rsq,
                                              unsigned short* __restrict__ ahi) {
    int row = blockIdx.x;
    int t = threadIdx.x;
    __shared__ float sq[DIM];
    float4 r = *(const float4*)(h + (size_t)row * DIM + t * 4);
    *(float4*)(rout + (size_t)row * DIM + t * 4) = r;
    ushort4 hv;
    hv.x = f2bf(r.x); hv.y = f2bf(r.y); hv.z = f2bf(r.z); hv.w = f2bf(r.w);
    *(ushort4*)(ahi + (size_t)row * DIM + t * 4) = hv;
    sq[t * 4 + 0] = __fmul_rn(r.x, r.x);
    sq[t * 4 + 1] = __fmul_rn(r.y, r.y);
    sq[t * 4 + 2] = __fmul_rn(r.z, r.z);
    sq[t * 4 + 3] = __fmul_rn(r.w, r.w);
    __syncthreads();
    if (t < 32) {
        int base = (t >> 3) * 128 + (t & 7);
        float s = sq[base];
#pragma unroll
        for (int m = 1; m < 16; ++m) s = __fadd_rn(s, sq[base + 8 * m]);
        s = pw_combine(s);
        if (t == 0) rsq[row] = s;
    }
}

// ---------------------------------------------------------------------------
// staging: A tile [256][64]bf16 (32KB) + B tile (32KB) = 2048 16B-chunks each,
// 4 iters x 512 threads. LDS dest LINEAR; chunk swizzle (c ^ (row&7)) applied
// to the GLOBAL source (both-sides rule). Validated round 7.
__device__ inline void stage_tile(const char* Abase, const char* Bbase,
                                  char* buf, int tid, int k0b) {
#pragma unroll
    for (int i = 0; i < 4; ++i) {
        int L = i * 512 + tid;
        int row = L >> 3, cc = L & 7;
        int sw = ((cc ^ (row & 7)) << 4);
        gload16(Abase + (size_t)row * (DIM * 2) + k0b + sw, buf + L * 16);
        gload16(Bbase + (size_t)row * (DIM * 2) + k0b + sw, buf + 32768 + L * 16);
    }
}

// ---------------------------------------------------------------------------
// phase-1: bf16 MFMA GEMM, 256x256 tile, BK=64, 8 waves, SINGLE-buffered LDS
// (~68.6KB -> 2 blocks/CU; cross-block overlap hides the staging drain, m97
// mechanism). dist' = csq - 2*dot~, per-row running top-4 per col-half.
__global__ __launch_bounds__(512) void k_gemm(const unsigned short* __restrict__ Ahi,
                                              const unsigned short* __restrict__ Bcb,
                                              const float* __restrict__ csq,
                                              float* __restrict__ partD,   // [NROWS][64]
                                              int* __restrict__ partI) {
    __shared__ __align__(16) char lds[67584];   // union: stage 64KB | dist [256][66] f32
    __shared__ float csqS[256];

    const int tid = threadIdx.x;
    const int lane = tid & 63;
    const int w = tid >> 6;
    const int wr = w >> 2;      // 0..1 : 128-row half
    const int wc = w & 3;       // 0..3 : 64-col group

    // XCD-aware decode: presumed XCD = wg&7 owns 16 contiguous row panels
    // (A set = 4MB = one L2) and sweeps the 8 bin tiles sequentially.
    const int wg = blockIdx.x;
    const int panel = (wg & 7) * 16 + ((wg >> 3) & 15);   // 0..127
    const int T = wg >> 7;                                 // 0..7

    if (tid < 256) csqS[tid] = csq[T * 256 + tid];

    const char* Abase = (const char*)(Ahi + (size_t)panel * 256 * DIM);
    const char* Bbase = (const char*)(Bcb + (size_t)T * 256 * DIM);

    f32x4 acc[8][4];
#pragma unroll
    for (int m = 0; m < 8; ++m)
#pragma unroll
        for (int n = 0; n < 4; ++n) acc[m][n] = (f32x4){0.f, 0.f, 0.f, 0.f};

    for (int ks = 0; ks < 8; ++ks) {
        __syncthreads();                       // all waves done reading prev tile
        stage_tile(Abase, Bbase, lds, tid, ks * 128);
        __syncthreads();                       // staged tile visible
        __builtin_amdgcn_s_setprio(1);
        const char* Ab = lds;
        const char* Bb = lds + 32768;
#pragma unroll
        for (int kk = 0; kk < 2; ++kk) {
            const int sw = (((kk * 4 + (lane >> 4)) ^ (lane & 7)) << 4);
            short8v bF[4];
#pragma unroll
            for (int n = 0; n < 4; ++n) {
                int rowB = wc * 64 + n * 16 + (lane & 15);
                bF[n] = *(const short8v*)(Bb + rowB * 128 + sw);
            }
#pragma unroll
            for (int m = 0; m < 8; ++m) {
                int rowA = wr * 128 + m * 16 + (lane & 15);
                short8v aF = *(const short8v*)(Ab + rowA * 128 + sw);
#pragma unroll
                for (int n = 0; n < 4; ++n)
                    acc[m][n] = __builtin_amdgcn_mfma_f32_16x16x32_bf16(
                        aF, bF[n], acc[m][n], 0, 0, 0);
            }
        }
        __builtin_amdgcn_s_setprio(0);
    }

    // epilogue: 4 phases through a [256][66] f32 LDS tile (reuses staging LDS).
    // Thread (row2,h) keeps a running top-4 over its 128 scanned cols;
    // two top-4s per row per tile stored (8 candidates/tile). Validated r7.
    float td0 = 3.4e38f, td1 = 3.4e38f, td2 = 3.4e38f, td3 = 3.4e38f;
    int ti0 = 0, ti1 = 0, ti2 = 0, ti3 = 0;
    float* distf = (float*)lds;
    const int row2 = tid >> 1, h = tid & 1;

#pragma unroll
    for (int p = 0; p < 4; ++p) {
        __syncthreads();
        if (wc == p) {
#pragma unroll
            for (int m = 0; m < 8; ++m)
#pragma unroll
                for (int n = 0; n < 4; ++n)
#pragma unroll
                    for (int r = 0; r < 4; ++r) {
                        int row = wr * 128 + m * 16 + (lane >> 4) * 4 + r;
                        int cl = n * 16 + (lane & 15);
                        distf[row * 66 + cl] = csqS[p * 64 + cl] - 2.0f * acc[m][n][r];
                    }
        }
        __syncthreads();
        int binb = T * 256 + p * 64 + h * 32;
        for (int c = 0; c < 32; ++c) {
            float d = distf[row2 * 66 + h * 32 + c];
            int bin = binb + c;
            if (d < td3) {
                if (d < td2) {
                    td3 = td2; ti3 = ti2;
                    if (d < td1) {
                        td2 = td1; ti2 = ti1;
                        if (d < td0) { td1 = td0; ti1 = ti0; td0 = d; ti0 = bin; }
                        else { td1 = d; ti1 = bin; }
                    } else { td2 = d; ti2 = bin; }
                } else { td3 = d; ti3 = bin; }
            }
        }
    }
    size_t g = ((size_t)panel * 256 + row2) * 64 + T * 8 + h * 4;
    partD[g + 0] = td0; partI[g + 0] = ti0;
    partD[g + 1] = td1; partI[g + 1] = ti1;
    partD[g + 2] = td2; partI[g + 2] = ti2;
    partD[g + 3] = td3; partI[g + 3] = ti3;
}

// ---------------------------------------------------------------------------
// fused phase-2: resolve argmin (validated margin/exact path) then update the
// residual + rsq + bf16 copy, one 128-thread block per row.
__global__ __launch_bounds__(128) void k_ru(const float* __restrict__ partD,
                                            const int* __restrict__ partI,
                                            float* __restrict__ resid,      // in/out
                                            float* __restrict__ rsq,        // in/out
                                            const float* __restrict__ csq,  // stage [NBINS]
                                            const float* __restrict__ cb,   // stage fp32
                                            float* __restrict__ codeOut,
                                            unsigned short* __restrict__ ahi) {
    const int row = blockIdx.x;
    const int t = threadIdx.x;
    __shared__ int sIdx;
    __shared__ float sq[DIM];

    if (t < 64) {
        float d = partD[(size_t)row * 64 + t];
        int bi0 = partI[(size_t)row * 64 + t];

        float bd = d; int bix = bi0;
#pragma unroll
        for (int o = 32; o > 0; o >>= 1) {
            float od = __shfl_xor(bd, o);
            int oi = __shfl_xor(bix, o);
            if (od < bd || (od == bd && oi < bix)) { bd = od; bix = oi; }
        }
        bool cand = (d <= bd + MARGIN);
        unsigned long long mask = __ballot(cand);
        int winI;
        if (__popcll(mask) == 1) {
            winI = bix;
        } else {
            float myD = 3.4e38f; int myI = 0x7fffffff;
            if (cand) {
                const float* rp = resid + (size_t)row * DIM;
                const float* cp = cb + (size_t)bi0 * DIM;
                float acc = 0.0f;
                for (int k = 0; k < DIM; k += 4) {
                    float4 rv = *(const float4*)(rp + k);
                    float4 cv = *(const float4*)(cp + k);
                    acc = fmaf(rv.x, cv.x, acc);
                    acc = fmaf(rv.y, cv.y, acc);
                    acc = fmaf(rv.z, cv.z, acc);
                    acc = fmaf(rv.w, cv.w, acc);
                }
                myD = __fadd_rn(__fsub_rn(rsq[row], __fmul_rn(2.0f, acc)), csq[bi0]);
                myI = bi0;
            }
#pragma unroll
            for (int o = 32; o > 0; o >>= 1) {
                float od = __shfl_xor(myD, o);
                int oi = __shfl_xor(myI, o);
                if (od < myD || (od == myD && oi < myI)) { myD = od; myI = oi; }
            }
            winI = myI;
        }
        if (t == 0) {
            sIdx = winI;
            codeOut[row] = (float)winI;
        }
    }
    __syncthreads();
    const int id = sIdx;

    // exact fp32 residual update + np-exact rsq + bf16 copy (validated round 4)
    float4 r = *(const float4*)(resid + (size_t)row * DIM + t * 4);
    float4 c = *(const float4*)(cb + (size_t)id * DIM + t * 4);
    r.x = __fsub_rn(r.x, c.x);
    r.y = __fsub_rn(r.y, c.y);
    r.z = __fsub_rn(r.z, c.z);
    r.w = __fsub_rn(r.w, c.w);
    *(float4*)(resid + (size_t)row * DIM + t * 4) = r;
    ushort4 hv;
    hv.x = f2bf(r.x); hv.y = f2bf(r.y); hv.z = f2bf(r.z); hv.w = f2bf(r.w);
    *(ushort4*)(ahi + (size_t)row * DIM + t * 4) = hv;

    sq[t * 4 + 0] = __fmul_rn(r.x, r.x);
    sq[t * 4 + 1] = __fmul_rn(r.y, r.y);
    sq[t * 4 + 2] = __fmul_rn(r.z, r.z);
    sq[t * 4 + 3] = __fmul_rn(r.w, r.w);
    __syncthreads();
    if (t < 32) {
        int base = (t >> 3) * 128 + (t & 7);
        float s = sq[base];
#pragma unroll
        for (int m = 1; m < 16; ++m) s = __fadd_rn(s, sq[base + 8 * m]);
        s = pw_combine(s);
        if (t == 0) rsq[row] = s;
    }
}

// ---------------------------------------------------------------------------
// quantized = hidden - residual, IN PLACE (residual lives in the quant region)
__global__ __launch_bounds__(256) void k_quant(const float* __restrict__ h,
                                               float* __restrict__ q) {
    size_t base = ((size_t)blockIdx.x * 256 + threadIdx.x) * 4;
    float4 rv = *(const float4*)(q + base);
    float4 hv = *(const float4*)(h + base);
    float4 o;
    o.x = __fsub_rn(hv.x, rv.x);
    o.y = __fsub_rn(hv.y, rv.y);
    o.z = __fsub_rn(hv.z, rv.z);
    o.w = __fsub_rn(hv.w, rv.w);
    *(float4*)(q + base) = o;
}

// ---------------------------------------------------------------------------
extern "C" void kernel_launch(void* const* d_in, const int* in_sizes, int n_in,
                              void* d_out, int out_size, void* d_ws, size_t ws_size,
                              hipStream_t stream) {
    const float* hidden = (const float*)d_in[0];   // [NROWS][DIM]
    const float* cbs = (const float*)d_in[1];      // [NQ][NBINS][DIM]

    float* out_codes = (float*)d_out;                          // [NQ][NROWS]
    float* resid = out_codes + (size_t)NQ * NROWS;             // quant region doubles as residual

    // workspace (~67 MB)
    unsigned short* Ahi = (unsigned short*)d_ws;               // NROWS*DIM bf16
    unsigned short* Cbf = Ahi + (size_t)NROWS * DIM;           // NQ*NBINS*DIM bf16
    float* csq32 = (float*)(Cbf + (size_t)NQ * NBINS * DIM);   // NQ*NBINS
    float* rsq = csq32 + (size_t)NQ * NBINS;                   // NROWS
    float* partD = rsq + NROWS;                                // NROWS*64
    int* partI = (int*)(partD + (size_t)NROWS * 64);           // NROWS*64

    k_csq<<<NQ * NBINS / 4, 256, 0, stream>>>(cbs, csq32);
    k_cbf<<<(int)((size_t)NQ * NBINS * DIM / 8 / 256), 256, 0, stream>>>(cbs, Cbf);
    k_init<<<NROWS, 128, 0, stream>>>(hidden, resid, rsq, Ahi);

    for (int s = 0; s < NQ; ++s) {
        const float* cbS = cbs + (size_t)s * NBINS * DIM;
        k_gemm<<<(NROWS / 256) * NTILE2, 512, 0, stream>>>(
            Ahi, Cbf + (size_t)s * NBINS * DIM, csq32 + (size_t)s * NBINS,
            partD, partI);
        k_ru<<<NROWS, 128, 0, stream>>>(partD, partI, resid, rsq,
                                        csq32 + (size_t)s * NBINS, cbS,
                                        out_codes + (size_t)s * NROWS, Ahi);
    }
    k_quant<<<NROWS * DIM / 4 / 256, 256, 0, stream>>>(hidden, resid);
}